// Round 1
// baseline (282.456 us; speedup 1.0000x reference)
//
#include <hip/hip_runtime.h>
#include <stdint.h>

// Problem constants: B=2, N=2048, A=256, H=8, KD=VD=32
#define NTOK 2048
#define SCALE 0.17677669529663687f  // 1/sqrt(32)

typedef short s16x8 __attribute__((ext_vector_type(8)));      // MFMA A/B frag (8 bf16)
typedef unsigned short u16x8 __attribute__((ext_vector_type(8)));
typedef float f32x4 __attribute__((ext_vector_type(4)));      // MFMA C/D frag

__device__ __forceinline__ unsigned short f2bf(float f) {
  unsigned int u = __builtin_bit_cast(unsigned int, f);
  u += 0x7fffu + ((u >> 16) & 1u);  // RNE
  return (unsigned short)(u >> 16);
}

// ---------------- Kernel 1: weight transpose + bf16 convert ----------------
// Input  W_p[a][h*32+c] fp32 (a-major). Output Wt[p][n][a] bf16, n=h*32+c.
// Transposed so proj-GEMM B-fragments (n=lane&15, k=a=quad*8+j) are contiguous 16B.
__global__ __launch_bounds__(256) void prep_weights_k(
    const float* __restrict__ qw, const float* __restrict__ kw,
    const float* __restrict__ vw, const float* __restrict__ gw,
    unsigned short* __restrict__ Wt) {
  __shared__ float tile[64][68];
  const int p = blockIdx.z;
  const int a0 = blockIdx.x * 64;
  const int n0 = blockIdx.y * 64;
  const float* src = (p == 0) ? qw : (p == 1) ? kw : (p == 2) ? vw : gw;
  const int tx = threadIdx.x & 15;
  const int ty = threadIdx.x >> 4;
#pragma unroll
  for (int kk = 0; kk < 4; kk++) {
    int ar = ty + kk * 16;
    float4 v = *reinterpret_cast<const float4*>(src + (a0 + ar) * 256 + n0 + tx * 4);
    tile[ar][tx * 4 + 0] = v.x; tile[ar][tx * 4 + 1] = v.y;
    tile[ar][tx * 4 + 2] = v.z; tile[ar][tx * 4 + 3] = v.w;
  }
  __syncthreads();
  unsigned short* dst = Wt + p * 65536;
#pragma unroll
  for (int kk = 0; kk < 4; kk++) {
    int nr = ty + kk * 16;
    ushort4 o;
    o.x = f2bf(tile[tx * 4 + 0][nr]);
    o.y = f2bf(tile[tx * 4 + 1][nr]);
    o.z = f2bf(tile[tx * 4 + 2][nr]);
    o.w = f2bf(tile[tx * 4 + 3][nr]);
    *reinterpret_cast<ushort4*>(dst + (n0 + nr) * 256 + a0 + tx * 4) = o;
  }
}

// ---------------- Kernel 2: fused QKVG projection GEMM (bf16 MFMA) ----------
// X[4096,256] fp32 x Wt[p][256,256] bf16 -> per-projection epilogues:
//  p=0: Qg[b][h][n][32] bf16 = (x.qw + query_b)*SCALE
//  p=1: Kg[b][h][n][32] bf16
//  p=2: Vt[b][h][32][n] bf16 (transposed for PV B-frags)
//  p=3: gate[b][n][256] fp32 = sigmoid(x.gw)
// Block: 256 thr (4 waves), M-tile 128 rows, 128 cols of one projection.
__global__ __launch_bounds__(256) void proj_k(
    const float* __restrict__ x, const unsigned short* __restrict__ Wt,
    const float* __restrict__ query_b,
    unsigned short* __restrict__ Qg, unsigned short* __restrict__ Kg,
    unsigned short* __restrict__ Vt, float* __restrict__ gate) {
  const int w = threadIdx.x >> 6;
  const int lane = threadIdx.x & 63;
  const int l15 = lane & 15;
  const int quad = lane >> 4;
  const int p = blockIdx.y >> 1;
  const int half = blockIdx.y & 1;
  const int rbase = blockIdx.x * 128 + w * 32;
  const unsigned short* wp = Wt + p * 65536;

  f32x4 acc[2][8];
#pragma unroll
  for (int rt = 0; rt < 2; rt++)
#pragma unroll
    for (int ct = 0; ct < 8; ct++) acc[rt][ct] = (f32x4){0.f, 0.f, 0.f, 0.f};

  for (int ks = 0; ks < 8; ks++) {
    const int kb = ks * 32;
    s16x8 af[2];
#pragma unroll
    for (int rt = 0; rt < 2; rt++) {
      const float* xr = x + (rbase + rt * 16 + l15) * 256 + kb + quad * 8;
      float4 f0 = *reinterpret_cast<const float4*>(xr);
      float4 f1 = *reinterpret_cast<const float4*>(xr + 4);
      u16x8 t;
      t[0] = f2bf(f0.x); t[1] = f2bf(f0.y); t[2] = f2bf(f0.z); t[3] = f2bf(f0.w);
      t[4] = f2bf(f1.x); t[5] = f2bf(f1.y); t[6] = f2bf(f1.z); t[7] = f2bf(f1.w);
      af[rt] = __builtin_bit_cast(s16x8, t);
    }
#pragma unroll
    for (int ct = 0; ct < 8; ct++) {
      uint4 bv = *reinterpret_cast<const uint4*>(
          wp + (half * 128 + ct * 16 + l15) * 256 + kb + quad * 8);
      s16x8 bfr = __builtin_bit_cast(s16x8, bv);
#pragma unroll
      for (int rt = 0; rt < 2; rt++)
        acc[rt][ct] = __builtin_amdgcn_mfma_f32_16x16x32_bf16(af[rt], bfr, acc[rt][ct], 0, 0, 0);
    }
  }

  // Epilogue. C/D layout: col = l15 (+16*ct), row = quad*4 + i (+16*rt).
#pragma unroll
  for (int ct = 0; ct < 8; ct++) {
    const int cgl = half * 128 + ct * 16 + l15;  // column within projection [0,256)
    const int h = cgl >> 5, c = cgl & 31;
#pragma unroll
    for (int rt = 0; rt < 2; rt++) {
      const int n0r = rbase + rt * 16 + quad * 4;  // token index of i=0
      const int bidx = n0r >> 11;
      const int nl0 = n0r & 2047;
      if (p == 0) {
        const float qb = query_b[cgl];
#pragma unroll
        for (int i = 0; i < 4; i++) {
          float v = (acc[rt][ct][i] + qb) * SCALE;
          Qg[(size_t)((bidx * 8 + h) * 2048 + nl0 + i) * 32 + c] = f2bf(v);
        }
      } else if (p == 1) {
#pragma unroll
        for (int i = 0; i < 4; i++)
          Kg[(size_t)((bidx * 8 + h) * 2048 + nl0 + i) * 32 + c] = f2bf(acc[rt][ct][i]);
      } else if (p == 2) {
        ushort4 o;
        o.x = f2bf(acc[rt][ct][0]); o.y = f2bf(acc[rt][ct][1]);
        o.z = f2bf(acc[rt][ct][2]); o.w = f2bf(acc[rt][ct][3]);
        *reinterpret_cast<ushort4*>(Vt + (size_t)((bidx * 8 + h) * 32 + c) * 2048 + nl0) = o;
      } else {
#pragma unroll
        for (int i = 0; i < 4; i++) {
          float s = 1.f / (1.f + __expf(-acc[rt][ct][i]));
          gate[(size_t)(bidx * 2048 + nl0 + i) * 256 + cgl] = s;
        }
      }
    }
  }
}

// ---------------- Kernel 3: flash attention + bias + gating -----------------
// Block: 128 thr (2 waves); wave owns 32 query rows. grid (32 qtiles, 8 h, 2 b).
// K_TILE=128 keys/iter, 16 iters. No __syncthreads: each wave's P slice private.
#define PST 136  // Ps row stride (128+8): 16B-aligned, 2-way-free bank pattern
__global__ __launch_bounds__(128) void attn_k(
    const unsigned short* __restrict__ Qg, const unsigned short* __restrict__ Kg,
    const unsigned short* __restrict__ Vt, const float* __restrict__ bias,
    const float* __restrict__ nb, const float* __restrict__ gate,
    float* __restrict__ out) {
  __shared__ unsigned short Ps[2 * 32 * PST];
  const int w = threadIdx.x >> 6;
  const int lane = threadIdx.x & 63;
  const int l15 = lane & 15;
  const int quad = lane >> 4;
  const int h = blockIdx.y, b = blockIdx.z;
  const int bh = b * 8 + h;
  const int qbase = blockIdx.x * 64 + w * 32;
  const unsigned short* Qp = Qg + (size_t)bh * 2048 * 32;
  const unsigned short* Kp = Kg + (size_t)bh * 2048 * 32;
  const unsigned short* Vp = Vt + (size_t)bh * 32 * 2048;
  const float* nbp = nb + (size_t)h * 2048 * 2048;
  const float* biasp = bias + b * 2048;
  unsigned short* Pw = Ps + w * 32 * PST;

  // Q A-frags: A[m=l15][k=quad*8+j], fixed for whole K loop.
  s16x8 aq[2];
#pragma unroll
  for (int rt = 0; rt < 2; rt++)
    aq[rt] = __builtin_bit_cast(s16x8, *reinterpret_cast<const uint4*>(
        Qp + (size_t)(qbase + rt * 16 + l15) * 32 + quad * 8));

  float mst[2][4], lst[2][4];
  f32x4 o[2][2];
#pragma unroll
  for (int rt = 0; rt < 2; rt++)
#pragma unroll
    for (int i = 0; i < 4; i++) { mst[rt][i] = -INFINITY; lst[rt][i] = 0.f; }
#pragma unroll
  for (int rt = 0; rt < 2; rt++)
#pragma unroll
    for (int vt = 0; vt < 2; vt++) o[rt][vt] = (f32x4){0.f, 0.f, 0.f, 0.f};

  for (int kt = 0; kt < 16; kt++) {
    const int kb = kt * 128;
    // K B-frags: B[k=c][n=key], key=l15 -> contiguous 16B rows of Kg.
    s16x8 bk[8];
#pragma unroll
    for (int ct = 0; ct < 8; ct++)
      bk[ct] = __builtin_bit_cast(s16x8, *reinterpret_cast<const uint4*>(
          Kp + (size_t)(kb + ct * 16 + l15) * 32 + quad * 8));
    // S = Q K^T  (one MFMA per 16x16 tile: K=32 = full head dim)
    f32x4 s[2][8];
#pragma unroll
    for (int rt = 0; rt < 2; rt++)
#pragma unroll
      for (int ct = 0; ct < 8; ct++)
        s[rt][ct] = __builtin_amdgcn_mfma_f32_16x16x32_bf16(
            aq[rt], bk[ct], (f32x4){0.f, 0.f, 0.f, 0.f}, 0, 0, 0);

    float bcol[8];
#pragma unroll
    for (int ct = 0; ct < 8; ct++) bcol[ct] = biasp[kb + ct * 16 + l15];

#pragma unroll
    for (int rt = 0; rt < 2; rt++) {
      const int qr0 = qbase + rt * 16 + quad * 4;
      // nonbatched_bias in C-layout registers (the 128MB stream)
      float nbv[8][4];
#pragma unroll
      for (int ct = 0; ct < 8; ct++)
#pragma unroll
        for (int i = 0; i < 4; i++)
          nbv[ct][i] = nbp[(size_t)(qr0 + i) * 2048 + kb + ct * 16 + l15];
#pragma unroll
      for (int ct = 0; ct < 8; ct++)
#pragma unroll
        for (int i = 0; i < 4; i++) s[rt][ct][i] += bcol[ct] + nbv[ct][i];

      float alpha[4];
#pragma unroll
      for (int i = 0; i < 4; i++) {
        float mx = s[rt][0][i];
#pragma unroll
        for (int ct = 1; ct < 8; ct++) mx = fmaxf(mx, s[rt][ct][i]);
        mx = fmaxf(mx, __shfl_xor(mx, 1));
        mx = fmaxf(mx, __shfl_xor(mx, 2));
        mx = fmaxf(mx, __shfl_xor(mx, 4));
        mx = fmaxf(mx, __shfl_xor(mx, 8));
        float mn = fmaxf(mst[rt][i], mx);
        alpha[i] = __expf(mst[rt][i] - mn);
        mst[rt][i] = mn;
        float sum = 0.f;
#pragma unroll
        for (int ct = 0; ct < 8; ct++) {
          float pv = __expf(s[rt][ct][i] - mn);
          Pw[(rt * 16 + quad * 4 + i) * PST + ct * 16 + l15] = f2bf(pv);
          sum += pv;
        }
        sum += __shfl_xor(sum, 1);
        sum += __shfl_xor(sum, 2);
        sum += __shfl_xor(sum, 4);
        sum += __shfl_xor(sum, 8);
        lst[rt][i] = lst[rt][i] * alpha[i] + sum;
      }
#pragma unroll
      for (int vt = 0; vt < 2; vt++)
#pragma unroll
        for (int i = 0; i < 4; i++) o[rt][vt][i] *= alpha[i];
    }

    // PV: A = P from LDS (b128 reads), B = V^T from global (contiguous 16B).
    s16x8 vbf[4][2];
#pragma unroll
    for (int kc = 0; kc < 4; kc++)
#pragma unroll
      for (int vt = 0; vt < 2; vt++)
        vbf[kc][vt] = __builtin_bit_cast(s16x8, *reinterpret_cast<const uint4*>(
            Vp + (size_t)(vt * 16 + l15) * 2048 + kb + kc * 32 + quad * 8));
#pragma unroll
    for (int rt = 0; rt < 2; rt++)
#pragma unroll
      for (int kc = 0; kc < 4; kc++) {
        s16x8 ap = __builtin_bit_cast(s16x8, *reinterpret_cast<const uint4*>(
            &Pw[(rt * 16 + l15) * PST + kc * 32 + quad * 8]));
#pragma unroll
        for (int vt = 0; vt < 2; vt++)
          o[rt][vt] = __builtin_amdgcn_mfma_f32_16x16x32_bf16(ap, vbf[kc][vt], o[rt][vt], 0, 0, 0);
      }
  }

  // Epilogue: normalize, gate, store fp32 out[b][q][h][v].
#pragma unroll
  for (int rt = 0; rt < 2; rt++) {
    const int qr0 = qbase + rt * 16 + quad * 4;
#pragma unroll
    for (int vt = 0; vt < 2; vt++)
#pragma unroll
      for (int i = 0; i < 4; i++) {
        const int q = qr0 + i;
        const int v = vt * 16 + l15;
        const size_t oidx = (size_t)(b * 2048 + q) * 256 + h * 32 + v;
        out[oidx] = (o[rt][vt][i] / lst[rt][i]) * gate[oidx];
      }
  }
}

// ---------------- launch ----------------------------------------------------
extern "C" void kernel_launch(void* const* d_in, const int* in_sizes, int n_in,
                              void* d_out, int out_size, void* d_ws, size_t ws_size,
                              hipStream_t stream) {
  const float* q_data = (const float*)d_in[0];
  const float* bias = (const float*)d_in[1];
  const float* nbb = (const float*)d_in[2];
  const float* qw = (const float*)d_in[3];
  const float* qb = (const float*)d_in[4];
  const float* kw = (const float*)d_in[5];
  const float* vw = (const float*)d_in[6];
  const float* gw = (const float*)d_in[7];
  float* out = (float*)d_out;

  char* ws = (char*)d_ws;
  // ws layout (10.5 MB total): Wt 512KB | Qg 2MB | Kg 2MB | Vt 2MB | gate 4MB
  unsigned short* Wt = (unsigned short*)(ws + 0);
  unsigned short* Qg = (unsigned short*)(ws + 524288);
  unsigned short* Kg = (unsigned short*)(ws + 2621440);
  unsigned short* Vt = (unsigned short*)(ws + 4718592);
  float* gate = (float*)(ws + 6815744);

  prep_weights_k<<<dim3(4, 4, 4), 256, 0, stream>>>(qw, kw, vw, gw, Wt);
  proj_k<<<dim3(32, 8), 256, 0, stream>>>(q_data, Wt, qb, Qg, Kg, Vt, gate);
  attn_k<<<dim3(32, 8, 2), 128, 0, stream>>>(Qg, Kg, Vt, bias, nbb, gate, out);
}

// Round 2
// 260.976 us; speedup vs baseline: 1.0823x; 1.0823x over previous
//
#include <hip/hip_runtime.h>
#include <stdint.h>

// Problem constants: B=2, N=2048, A=256, H=8, KD=VD=32
#define NTOK 2048
#define SCALE 0.17677669529663687f  // 1/sqrt(32)

typedef short s16x8 __attribute__((ext_vector_type(8)));      // MFMA A/B frag (8 bf16)
typedef unsigned short u16x8 __attribute__((ext_vector_type(8)));
typedef float f32x4 __attribute__((ext_vector_type(4)));      // MFMA C/D frag

__device__ __forceinline__ unsigned short f2bf(float f) {
  unsigned int u = __builtin_bit_cast(unsigned int, f);
  u += 0x7fffu + ((u >> 16) & 1u);  // RNE
  return (unsigned short)(u >> 16);
}

// ---------------- Kernel 1: weight transpose + bf16 convert ----------------
// Input  W_p[a][h*32+c] fp32 (a-major). Output Wt[p][n][a] bf16, n=h*32+c.
__global__ __launch_bounds__(256) void prep_weights_k(
    const float* __restrict__ qw, const float* __restrict__ kw,
    const float* __restrict__ vw, const float* __restrict__ gw,
    unsigned short* __restrict__ Wt) {
  __shared__ float tile[64][68];
  const int p = blockIdx.z;
  const int a0 = blockIdx.x * 64;
  const int n0 = blockIdx.y * 64;
  const float* src = (p == 0) ? qw : (p == 1) ? kw : (p == 2) ? vw : gw;
  const int tx = threadIdx.x & 15;
  const int ty = threadIdx.x >> 4;
#pragma unroll
  for (int kk = 0; kk < 4; kk++) {
    int ar = ty + kk * 16;
    float4 v = *reinterpret_cast<const float4*>(src + (a0 + ar) * 256 + n0 + tx * 4);
    tile[ar][tx * 4 + 0] = v.x; tile[ar][tx * 4 + 1] = v.y;
    tile[ar][tx * 4 + 2] = v.z; tile[ar][tx * 4 + 3] = v.w;
  }
  __syncthreads();
  unsigned short* dst = Wt + p * 65536;
#pragma unroll
  for (int kk = 0; kk < 4; kk++) {
    int nr = ty + kk * 16;
    ushort4 o;
    o.x = f2bf(tile[tx * 4 + 0][nr]);
    o.y = f2bf(tile[tx * 4 + 1][nr]);
    o.z = f2bf(tile[tx * 4 + 2][nr]);
    o.w = f2bf(tile[tx * 4 + 3][nr]);
    *reinterpret_cast<ushort4*>(dst + (n0 + nr) * 256 + a0 + tx * 4) = o;
  }
}

// ---------------- Kernel 2: fused QKVG projection GEMM (bf16 MFMA) ----------
__global__ __launch_bounds__(256) void proj_k(
    const float* __restrict__ x, const unsigned short* __restrict__ Wt,
    const float* __restrict__ query_b,
    unsigned short* __restrict__ Qg, unsigned short* __restrict__ Kg,
    unsigned short* __restrict__ Vt, float* __restrict__ gate) {
  const int w = threadIdx.x >> 6;
  const int lane = threadIdx.x & 63;
  const int l15 = lane & 15;
  const int quad = lane >> 4;
  const int p = blockIdx.y >> 1;
  const int half = blockIdx.y & 1;
  const int rbase = blockIdx.x * 128 + w * 32;
  const unsigned short* wp = Wt + p * 65536;

  f32x4 acc[2][8];
#pragma unroll
  for (int rt = 0; rt < 2; rt++)
#pragma unroll
    for (int ct = 0; ct < 8; ct++) acc[rt][ct] = (f32x4){0.f, 0.f, 0.f, 0.f};

  for (int ks = 0; ks < 8; ks++) {
    const int kb = ks * 32;
    s16x8 af[2];
#pragma unroll
    for (int rt = 0; rt < 2; rt++) {
      const float* xr = x + (rbase + rt * 16 + l15) * 256 + kb + quad * 8;
      float4 f0 = *reinterpret_cast<const float4*>(xr);
      float4 f1 = *reinterpret_cast<const float4*>(xr + 4);
      u16x8 t;
      t[0] = f2bf(f0.x); t[1] = f2bf(f0.y); t[2] = f2bf(f0.z); t[3] = f2bf(f0.w);
      t[4] = f2bf(f1.x); t[5] = f2bf(f1.y); t[6] = f2bf(f1.z); t[7] = f2bf(f1.w);
      af[rt] = __builtin_bit_cast(s16x8, t);
    }
#pragma unroll
    for (int ct = 0; ct < 8; ct++) {
      uint4 bv = *reinterpret_cast<const uint4*>(
          wp + (half * 128 + ct * 16 + l15) * 256 + kb + quad * 8);
      s16x8 bfr = __builtin_bit_cast(s16x8, bv);
#pragma unroll
      for (int rt = 0; rt < 2; rt++)
        acc[rt][ct] = __builtin_amdgcn_mfma_f32_16x16x32_bf16(af[rt], bfr, acc[rt][ct], 0, 0, 0);
    }
  }

#pragma unroll
  for (int ct = 0; ct < 8; ct++) {
    const int cgl = half * 128 + ct * 16 + l15;
    const int h = cgl >> 5, c = cgl & 31;
#pragma unroll
    for (int rt = 0; rt < 2; rt++) {
      const int n0r = rbase + rt * 16 + quad * 4;
      const int bidx = n0r >> 11;
      const int nl0 = n0r & 2047;
      if (p == 0) {
        const float qb = query_b[cgl];
#pragma unroll
        for (int i = 0; i < 4; i++) {
          float v = (acc[rt][ct][i] + qb) * SCALE;
          Qg[(size_t)((bidx * 8 + h) * 2048 + nl0 + i) * 32 + c] = f2bf(v);
        }
      } else if (p == 1) {
#pragma unroll
        for (int i = 0; i < 4; i++)
          Kg[(size_t)((bidx * 8 + h) * 2048 + nl0 + i) * 32 + c] = f2bf(acc[rt][ct][i]);
      } else if (p == 2) {
        ushort4 o;
        o.x = f2bf(acc[rt][ct][0]); o.y = f2bf(acc[rt][ct][1]);
        o.z = f2bf(acc[rt][ct][2]); o.w = f2bf(acc[rt][ct][3]);
        *reinterpret_cast<ushort4*>(Vt + (size_t)((bidx * 8 + h) * 32 + c) * 2048 + nl0) = o;
      } else {
#pragma unroll
        for (int i = 0; i < 4; i++) {
          float s = 1.f / (1.f + __expf(-acc[rt][ct][i]));
          gate[(size_t)(bidx * 2048 + nl0 + i) * 256 + cgl] = s;
        }
      }
    }
  }
}

// ---------------- Kernel 3: flash attention + bias + gating -----------------
// v2: 16 q-rows per wave (2048 waves -> 8 waves/CU) + double-buffered register
// prefetch of the nonbatched-bias stream (the latency bottleneck).
// Block: 128 thr (2 waves). grid (64 qtiles, 8 h, 2 b). No __syncthreads.
#define PST 136  // Ps row stride in elements (16B-aligned rows)
__global__ __launch_bounds__(128, 2) void attn_k(
    const unsigned short* __restrict__ Qg, const unsigned short* __restrict__ Kg,
    const unsigned short* __restrict__ Vt, const float* __restrict__ bias,
    const float* __restrict__ nb, const float* __restrict__ gate,
    float* __restrict__ out) {
  __shared__ unsigned short Ps[2 * 16 * PST];
  const int w = threadIdx.x >> 6;
  const int lane = threadIdx.x & 63;
  const int l15 = lane & 15;
  const int quad = lane >> 4;
  const int h = blockIdx.y, b = blockIdx.z;
  const int bh = b * 8 + h;
  const int qbase = blockIdx.x * 32 + w * 16;
  const unsigned short* Qp = Qg + (size_t)bh * 2048 * 32;
  const unsigned short* Kp = Kg + (size_t)bh * 2048 * 32;
  const unsigned short* Vp = Vt + (size_t)bh * 32 * 2048;
  const float* nbp = nb + (size_t)h * 2048 * 2048;
  const float* biasp = bias + b * 2048;
  unsigned short* Pw = Ps + w * 16 * PST;

  // Q A-frag: A[m=l15][k=quad*8+j], fixed for whole K loop.
  s16x8 aq = __builtin_bit_cast(s16x8, *reinterpret_cast<const uint4*>(
      Qp + (size_t)(qbase + l15) * 32 + quad * 8));
  const int qr0 = qbase + quad * 4;  // C-layout row of i=0

  float mst[4], lst[4];
  f32x4 o[2];
#pragma unroll
  for (int i = 0; i < 4; i++) { mst[i] = -INFINITY; lst[i] = 0.f; }
#pragma unroll
  for (int vt = 0; vt < 2; vt++) o[vt] = (f32x4){0.f, 0.f, 0.f, 0.f};

  // Double-buffered registers for the 128MB nonbatched-bias stream + key bias.
  float nbuf[2][32];
  float bb[2][8];
#pragma unroll
  for (int ct = 0; ct < 8; ct++) {
    bb[0][ct] = biasp[ct * 16 + l15];
#pragma unroll
    for (int i = 0; i < 4; i++)
      nbuf[0][ct * 4 + i] = nbp[(size_t)(qr0 + i) * 2048 + ct * 16 + l15];
  }

#pragma unroll 2
  for (int kt = 0; kt < 16; kt++) {
    const int kb = kt * 128;
    const int cur = kt & 1, nxt = cur ^ 1;

    // K B-frags: B[k=c][n=key], key=l15 -> contiguous 16B rows of Kg.
    s16x8 bk[8];
#pragma unroll
    for (int ct = 0; ct < 8; ct++)
      bk[ct] = __builtin_bit_cast(s16x8, *reinterpret_cast<const uint4*>(
          Kp + (size_t)(kb + ct * 16 + l15) * 32 + quad * 8));

    // Prefetch next tile's nonbatched bias + key bias (hide HBM latency).
    if (kt < 15) {
      const int kb2 = kb + 128;
#pragma unroll
      for (int ct = 0; ct < 8; ct++) {
        bb[nxt][ct] = biasp[kb2 + ct * 16 + l15];
#pragma unroll
        for (int i = 0; i < 4; i++)
          nbuf[nxt][ct * 4 + i] = nbp[(size_t)(qr0 + i) * 2048 + kb2 + ct * 16 + l15];
      }
    }

    // S = Q K^T (one MFMA per 16x16 tile: K=32 = full head dim)
    f32x4 s[8];
#pragma unroll
    for (int ct = 0; ct < 8; ct++)
      s[ct] = __builtin_amdgcn_mfma_f32_16x16x32_bf16(
          aq, bk[ct], (f32x4){0.f, 0.f, 0.f, 0.f}, 0, 0, 0);

    // V B-frags for PV (L2-resident; issue early).
    s16x8 vbf[4][2];
#pragma unroll
    for (int kc = 0; kc < 4; kc++)
#pragma unroll
      for (int vt = 0; vt < 2; vt++)
        vbf[kc][vt] = __builtin_bit_cast(s16x8, *reinterpret_cast<const uint4*>(
            Vp + (size_t)(vt * 16 + l15) * 2048 + kb + kc * 32 + quad * 8));

    // Add biases (current buffers, loaded one tile ago - no wait).
#pragma unroll
    for (int ct = 0; ct < 8; ct++)
#pragma unroll
      for (int i = 0; i < 4; i++) s[ct][i] += bb[cur][ct] + nbuf[cur][ct * 4 + i];

    // Online softmax per row (16-lane reductions across the 8 ct groups).
    float alpha[4];
#pragma unroll
    for (int i = 0; i < 4; i++) {
      float mx = s[0][i];
#pragma unroll
      for (int ct = 1; ct < 8; ct++) mx = fmaxf(mx, s[ct][i]);
      mx = fmaxf(mx, __shfl_xor(mx, 1));
      mx = fmaxf(mx, __shfl_xor(mx, 2));
      mx = fmaxf(mx, __shfl_xor(mx, 4));
      mx = fmaxf(mx, __shfl_xor(mx, 8));
      float mn = fmaxf(mst[i], mx);
      alpha[i] = __expf(mst[i] - mn);
      mst[i] = mn;
      float sum = 0.f;
#pragma unroll
      for (int ct = 0; ct < 8; ct++) {
        float pv = __expf(s[ct][i] - mn);
        Pw[(quad * 4 + i) * PST + ct * 16 + l15] = f2bf(pv);
        sum += pv;
      }
      sum += __shfl_xor(sum, 1);
      sum += __shfl_xor(sum, 2);
      sum += __shfl_xor(sum, 4);
      sum += __shfl_xor(sum, 8);
      lst[i] = lst[i] * alpha[i] + sum;
    }
#pragma unroll
    for (int vt = 0; vt < 2; vt++)
#pragma unroll
      for (int i = 0; i < 4; i++) o[vt][i] *= alpha[i];

    // PV: A = P from LDS (b128 reads, wave-private slice), B = V^T frags.
#pragma unroll
    for (int kc = 0; kc < 4; kc++) {
      s16x8 ap = __builtin_bit_cast(s16x8, *reinterpret_cast<const uint4*>(
          &Pw[l15 * PST + kc * 32 + quad * 8]));
#pragma unroll
      for (int vt = 0; vt < 2; vt++)
        o[vt] = __builtin_amdgcn_mfma_f32_16x16x32_bf16(ap, vbf[kc][vt], o[vt], 0, 0, 0);
    }
  }

  // Epilogue: normalize, gate, store fp32 out[b][q][h][v].
#pragma unroll
  for (int vt = 0; vt < 2; vt++)
#pragma unroll
    for (int i = 0; i < 4; i++) {
      const int q = qr0 + i;
      const int v = vt * 16 + l15;
      const size_t oidx = (size_t)(b * 2048 + q) * 256 + h * 32 + v;
      out[oidx] = (o[vt][i] / lst[i]) * gate[oidx];
    }
}

// ---------------- launch ----------------------------------------------------
extern "C" void kernel_launch(void* const* d_in, const int* in_sizes, int n_in,
                              void* d_out, int out_size, void* d_ws, size_t ws_size,
                              hipStream_t stream) {
  const float* q_data = (const float*)d_in[0];
  const float* bias = (const float*)d_in[1];
  const float* nbb = (const float*)d_in[2];
  const float* qw = (const float*)d_in[3];
  const float* qb = (const float*)d_in[4];
  const float* kw = (const float*)d_in[5];
  const float* vw = (const float*)d_in[6];
  const float* gw = (const float*)d_in[7];
  float* out = (float*)d_out;

  char* ws = (char*)d_ws;
  // ws layout (10.5 MB total): Wt 512KB | Qg 2MB | Kg 2MB | Vt 2MB | gate 4MB
  unsigned short* Wt = (unsigned short*)(ws + 0);
  unsigned short* Qg = (unsigned short*)(ws + 524288);
  unsigned short* Kg = (unsigned short*)(ws + 2621440);
  unsigned short* Vt = (unsigned short*)(ws + 4718592);
  float* gate = (float*)(ws + 6815744);

  prep_weights_k<<<dim3(4, 4, 4), 256, 0, stream>>>(qw, kw, vw, gw, Wt);
  proj_k<<<dim3(32, 8), 256, 0, stream>>>(q_data, Wt, qb, Qg, Kg, Vt, gate);
  attn_k<<<dim3(64, 8, 2), 128, 0, stream>>>(Qg, Kg, Vt, bias, nbb, gate, out);
}